// Round 1
// baseline (354.769 us; speedup 1.0000x reference)
//
#include <hip/hip_runtime.h>
#include <math.h>

#define NUM_CLASSES 80
#define C_CH (NUM_CLASSES + 1)

__device__ __forceinline__ float softplusf(float x) {
    // stable log(1+e^x)
    return fmaxf(x, 0.f) + log1pf(expf(-fabsf(x)));
}
__device__ __forceinline__ float sigmoidf_(float x) {
    return 1.f / (1.f + expf(-x));
}

// ws layout (4-byte words):
// [0]=lb  [1]=lo_targets  [2]=lc  [3]=n
// [4]=bce_bg4 [5]=bgcnt4  [6]=bce_bg5 [7]=bgcnt5
// [8 ..)  bit-packed occupancy flags: p4 (B*6400 bits), then p5 (B*1600 bits)

__global__ void target_kernel(
    const float* __restrict__ cls_p4, const float* __restrict__ reg_p4,
    const float* __restrict__ cls_p5, const float* __restrict__ reg_p5,
    const int* __restrict__ t4_cls, const float* __restrict__ t4_box, const float* __restrict__ t4_mask,
    const int* __restrict__ t5_cls, const float* __restrict__ t5_box, const float* __restrict__ t5_mask,
    float* __restrict__ acc, unsigned int* __restrict__ flags4, unsigned int* __restrict__ flags5,
    int B, int T)
{
    const int BT = B * T;
    int bid = blockIdx.x;
    const int scale = (bid >= BT) ? 1 : 0;
    const int ti = scale ? bid - BT : bid;
    const int b = ti / T;

    const float* cls_p; const float* reg_p; const int* tc; const float* tb; const float* tm;
    unsigned int* flags; int H, W;
    if (!scale) { cls_p = cls_p4; reg_p = reg_p4; tc = t4_cls; tb = t4_box; tm = t4_mask; flags = flags4; H = 80; W = 80; }
    else        { cls_p = cls_p5; reg_p = reg_p5; tc = t5_cls; tb = t5_box; tm = t5_mask; flags = flags5; H = 40; W = 40; }
    const int HW = H * W;

    const float mask = tm[ti];
    const int   cid  = tc[ti];
    const float bx0 = tb[ti * 4 + 0], bx1 = tb[ti * 4 + 1];
    const float bx2 = tb[ti * 4 + 2], bx3 = tb[ti * 4 + 3];

    const float tx = bx0 * (float)W, ty = bx1 * (float)H;
    const float tw = bx2 * (float)W, th = bx3 * (float)H;
    const int gx = (int)fminf(fmaxf(tx, 0.f), (float)(W - 1));
    const int gy = (int)fminf(fmaxf(ty, 0.f), (float)(H - 1));
    const int cell = gy * W + gx;
    const int lane = threadIdx.x;

    // scatter occupancy (only targets with mask>0 mark the cell; matches .at[].max(mask))
    if (lane == 0 && mask > 0.f) {
        int gidx = b * HW + cell;
        atomicOr(&flags[gidx >> 5], 1u << (gidx & 31));
    }

    // focal loss over 80 classes, lane-parallel
    const float* cvbase = cls_p + (size_t)b * C_CH * HW + cell;
    float fsum = 0.f;
    for (int c = lane; c < NUM_CLASSES; c += 64) {
        float x   = cvbase[(size_t)(c + 1) * HW];
        float tgt = (c == cid) ? 1.f : 0.f;
        float bce = softplusf(x) - x * tgt;
        float p   = sigmoidf_(x);
        float pt  = p * tgt + (1.f - p) * (1.f - tgt);
        float om  = 1.f - pt;
        fsum += 0.25f * om * om * bce;
    }
    for (int off = 32; off > 0; off >>= 1) fsum += __shfl_down(fsum, off, 64);

    if (lane == 0) {
        float lc = (fsum * (1.f / (float)NUM_CLASSES)) * mask;

        float obj = cvbase[0];
        float lo  = softplusf(-obj) * mask;

        // bbox smooth-L1
        float rv0 = reg_p[(size_t)(b * 4 + 0) * HW + cell];
        float rv1 = reg_p[(size_t)(b * 4 + 1) * HW + cell];
        float rv2 = reg_p[(size_t)(b * 4 + 2) * HW + cell];
        float rv3 = reg_p[(size_t)(b * 4 + 3) * HW + cell];
        float dx = sigmoidf_(rv0), dy = sigmoidf_(rv1);
        float dw = expf(fminf(fmaxf(rv2, -4.f), 4.f));
        float dh = expf(fminf(fmaxf(rv3, -4.f), 4.f));
        float px = (float)gx + dx, py = (float)gy + dy;
        float pb0 = px - dw * 0.5f, pb1 = py - dh * 0.5f, pb2 = px + dw * 0.5f, pb3 = py + dh * 0.5f;
        float tb0 = tx - tw * 0.5f, tb1 = ty - th * 0.5f, tb2 = tx + tw * 0.5f, tb3 = ty + th * 0.5f;
        float s = 0.f;
        {
            float d, a;
            d = pb0 - tb0; a = fabsf(d); s += (a < 1.f) ? 0.5f * d * d : a - 0.5f;
            d = pb1 - tb1; a = fabsf(d); s += (a < 1.f) ? 0.5f * d * d : a - 0.5f;
            d = pb2 - tb2; a = fabsf(d); s += (a < 1.f) ? 0.5f * d * d : a - 0.5f;
            d = pb3 - tb3; a = fabsf(d); s += (a < 1.f) ? 0.5f * d * d : a - 0.5f;
        }
        float lb = (s * 0.25f) * mask;

        atomicAdd(&acc[0], lb);
        atomicAdd(&acc[1], lo);
        atomicAdd(&acc[2], lc);
        atomicAdd(&acc[3], mask);
    }
}

__global__ void bg_kernel(
    const float* __restrict__ cls_p4, const float* __restrict__ cls_p5,
    const unsigned int* __restrict__ flags4, const unsigned int* __restrict__ flags5,
    float* __restrict__ acc, int B, int nb4)
{
    const int scale = (blockIdx.x >= nb4) ? 1 : 0;
    const float* cls_p; const unsigned int* flags; int HW; int blk;
    if (!scale) { cls_p = cls_p4; flags = flags4; HW = 6400; blk = blockIdx.x; }
    else        { cls_p = cls_p5; flags = flags5; HW = 1600; blk = blockIdx.x - nb4; }
    const int N = B * HW;
    const int idx = blk * 256 + threadIdx.x;

    float sp = 0.f, cnt = 0.f;
    if (idx < N) {
        unsigned int w = flags[idx >> 5];
        if (!((w >> (idx & 31)) & 1u)) {
            int b = idx / HW, cell = idx - b * HW;
            float x = cls_p[(size_t)b * C_CH * HW + cell];  // channel 0
            sp = softplusf(x);
            cnt = 1.f;
        }
    }
    for (int off = 32; off > 0; off >>= 1) {
        sp  += __shfl_down(sp,  off, 64);
        cnt += __shfl_down(cnt, off, 64);
    }
    __shared__ float s_sp[4], s_cnt[4];
    const int wid = threadIdx.x >> 6;
    if ((threadIdx.x & 63) == 0) { s_sp[wid] = sp; s_cnt[wid] = cnt; }
    __syncthreads();
    if (threadIdx.x == 0) {
        float a = s_sp[0] + s_sp[1] + s_sp[2] + s_sp[3];
        float c = s_cnt[0] + s_cnt[1] + s_cnt[2] + s_cnt[3];
        atomicAdd(&acc[4 + 2 * scale], a);
        atomicAdd(&acc[5 + 2 * scale], c);
    }
}

__global__ void final_kernel(const float* __restrict__ acc, float* __restrict__ out)
{
    float lb = acc[0], lo = acc[1], lc = acc[2], n = acc[3];
    float b4 = acc[4], c4 = acc[5], b5 = acc[6], c5 = acc[7];
    lo += 0.05f * ((c4 > 0.f) ? b4 / fmaxf(c4, 1.f) : 0.f);
    lo += 0.05f * ((c5 > 0.f) ? b5 / fmaxf(c5, 1.f) : 0.f);
    float nd = fmaxf(n, 1.f);
    if (n > 0.f) { lb /= nd; lc /= nd; }
    lo /= fmaxf(n, 1.0f);
    out[0] = 2.0f * lb + 1.0f * lo + 0.5f * lc;
}

extern "C" void kernel_launch(void* const* d_in, const int* in_sizes, int n_in,
                              void* d_out, int out_size, void* d_ws, size_t ws_size,
                              hipStream_t stream) {
    const float* cls_p4 = (const float*)d_in[0];
    const float* reg_p4 = (const float*)d_in[1];
    const float* cls_p5 = (const float*)d_in[2];
    const float* reg_p5 = (const float*)d_in[3];
    const int*   t4_cls = (const int*)d_in[4];
    const float* t4_box = (const float*)d_in[5];
    const float* t4_mask= (const float*)d_in[6];
    const int*   t5_cls = (const int*)d_in[7];
    const float* t5_box = (const float*)d_in[8];
    const float* t5_mask= (const float*)d_in[9];

    const int B = in_sizes[0] / (C_CH * 6400);   // cls_p4: B x 81 x 80 x 80
    const int T = in_sizes[4] / B;               // t4_cls: B x T

    float* acc = (float*)d_ws;
    unsigned int* flags4 = (unsigned int*)d_ws + 8;
    const int fw4 = (B * 6400 + 31) / 32;
    unsigned int* flags5 = flags4 + fw4;
    const int fw5 = (B * 1600 + 31) / 32;

    const size_t zero_bytes = (size_t)(8 + fw4 + fw5) * sizeof(unsigned int);
    hipMemsetAsync(d_ws, 0, zero_bytes, stream);

    const int n_targets = 2 * B * T;
    target_kernel<<<n_targets, 64, 0, stream>>>(
        cls_p4, reg_p4, cls_p5, reg_p5,
        t4_cls, t4_box, t4_mask, t5_cls, t5_box, t5_mask,
        acc, flags4, flags5, B, T);

    const int nb4 = (B * 6400 + 255) / 256;
    const int nb5 = (B * 1600 + 255) / 256;
    bg_kernel<<<nb4 + nb5, 256, 0, stream>>>(cls_p4, cls_p5, flags4, flags5, acc, B, nb4);

    final_kernel<<<1, 1, 0, stream>>>(acc, (float*)d_out);
}

// Round 2
// 131.668 us; speedup vs baseline: 2.6944x; 2.6944x over previous
//
#include <hip/hip_runtime.h>
#include <math.h>

#define NUM_CLASSES 80
#define C_CH (NUM_CLASSES + 1)

__device__ __forceinline__ float softplusf(float x) {
    return fmaxf(x, 0.f) + log1pf(expf(-fabsf(x)));
}
__device__ __forceinline__ float sigmoidf_(float x) {
    return 1.f / (1.f + expf(-x));
}

// ws layout (4-byte words):
//   flags4  : (B*6400+31)/32 words   (bit-packed occupancy, p4)
//   flags5  : (B*1600+31)/32 words   (p5)
//   tpart   : nTblk*4 floats  {lb, lo, lc, n} per target-block
//   bgpart4 : nb4*2 floats    {softplus_sum, count} per bg-block (p4)
//   bgpart5 : nb5*2 floats    (p5)
// Only the flag region needs zeroing; all partial slots are written
// unconditionally by their owning block every call.

__global__ void target_kernel(
    const float* __restrict__ cls_p4, const float* __restrict__ reg_p4,
    const float* __restrict__ cls_p5, const float* __restrict__ reg_p5,
    const int* __restrict__ t4_cls, const float* __restrict__ t4_box, const float* __restrict__ t4_mask,
    const int* __restrict__ t5_cls, const float* __restrict__ t5_box, const float* __restrict__ t5_mask,
    float* __restrict__ tpart, unsigned int* __restrict__ flags4, unsigned int* __restrict__ flags5,
    int B, int T)
{
    const int BT = B * T;
    const int wave = threadIdx.x >> 6;
    const int lane = threadIdx.x & 63;
    const int tg = blockIdx.x * 4 + wave;   // global target index over both scales

    float lb = 0.f, lo = 0.f, lcv = 0.f, msum = 0.f;

    if (tg < 2 * BT) {
        const int scale = (tg >= BT) ? 1 : 0;
        const int ti = scale ? tg - BT : tg;
        const int b = ti / T;

        const float* cls_p; const float* reg_p; const int* tc; const float* tb_; const float* tm;
        unsigned int* flags; int H, W;
        if (!scale) { cls_p = cls_p4; reg_p = reg_p4; tc = t4_cls; tb_ = t4_box; tm = t4_mask; flags = flags4; H = 80; W = 80; }
        else        { cls_p = cls_p5; reg_p = reg_p5; tc = t5_cls; tb_ = t5_box; tm = t5_mask; flags = flags5; H = 40; W = 40; }
        const int HW = H * W;

        const float mask = tm[ti];
        const int   cid  = tc[ti];
        const float bx0 = tb_[ti * 4 + 0], bx1 = tb_[ti * 4 + 1];
        const float bx2 = tb_[ti * 4 + 2], bx3 = tb_[ti * 4 + 3];

        const float tx = bx0 * (float)W, ty = bx1 * (float)H;
        const float tw = bx2 * (float)W, th = bx3 * (float)H;
        const int gx = (int)fminf(fmaxf(tx, 0.f), (float)(W - 1));
        const int gy = (int)fminf(fmaxf(ty, 0.f), (float)(H - 1));
        const int cell = gy * W + gx;

        // scatter occupancy flag (addresses ~unique per target: low contention)
        if (lane == 0 && mask > 0.f) {
            int gidx = b * HW + cell;
            atomicOr(&flags[gidx >> 5], 1u << (gidx & 31));
        }

        const float* cvbase = cls_p + (size_t)b * C_CH * HW + cell;

        // issue reg + obj loads early on lanes 0..4 so they overlap the focal gather
        float rvq = 0.f;
        if (lane < 4) rvq = reg_p[(size_t)(b * 4 + lane) * HW + cell];
        float objq = (lane == 0) ? cvbase[0] : 0.f;

        // focal loss over 80 classes, lane-parallel
        float fsum = 0.f;
        for (int c = lane; c < NUM_CLASSES; c += 64) {
            float x   = cvbase[(size_t)(c + 1) * HW];
            float tgt = (c == cid) ? 1.f : 0.f;
            float bce = softplusf(x) - x * tgt;
            float p   = sigmoidf_(x);
            float pt  = p * tgt + (1.f - p) * (1.f - tgt);
            float om  = 1.f - pt;
            fsum += 0.25f * om * om * bce;
        }
        for (int off = 32; off > 0; off >>= 1) fsum += __shfl_down(fsum, off, 64);

        float rv0 = __shfl(rvq, 0, 64), rv1 = __shfl(rvq, 1, 64);
        float rv2 = __shfl(rvq, 2, 64), rv3 = __shfl(rvq, 3, 64);

        if (lane == 0) {
            lcv = (fsum * (1.f / (float)NUM_CLASSES)) * mask;
            lo  = softplusf(-objq) * mask;

            float dx = sigmoidf_(rv0), dy = sigmoidf_(rv1);
            float dw = expf(fminf(fmaxf(rv2, -4.f), 4.f));
            float dh = expf(fminf(fmaxf(rv3, -4.f), 4.f));
            float px = (float)gx + dx, py = (float)gy + dy;
            float pb0 = px - dw * 0.5f, pb1 = py - dh * 0.5f, pb2 = px + dw * 0.5f, pb3 = py + dh * 0.5f;
            float tb0 = tx - tw * 0.5f, tb1 = ty - th * 0.5f, tb2 = tx + tw * 0.5f, tb3 = ty + th * 0.5f;
            float s = 0.f, d, a;
            d = pb0 - tb0; a = fabsf(d); s += (a < 1.f) ? 0.5f * d * d : a - 0.5f;
            d = pb1 - tb1; a = fabsf(d); s += (a < 1.f) ? 0.5f * d * d : a - 0.5f;
            d = pb2 - tb2; a = fabsf(d); s += (a < 1.f) ? 0.5f * d * d : a - 0.5f;
            d = pb3 - tb3; a = fabsf(d); s += (a < 1.f) ? 0.5f * d * d : a - 0.5f;
            lb = (s * 0.25f) * mask;
            msum = mask;
        }
    }

    __shared__ float s4[4][4];
    if (lane == 0) { s4[wave][0] = lb; s4[wave][1] = lo; s4[wave][2] = lcv; s4[wave][3] = msum; }
    __syncthreads();
    if (threadIdx.x < 4) {
        float v = s4[0][threadIdx.x] + s4[1][threadIdx.x] + s4[2][threadIdx.x] + s4[3][threadIdx.x];
        tpart[blockIdx.x * 4 + threadIdx.x] = v;
    }
}

__global__ void bg_kernel(
    const float* __restrict__ cls_p4, const float* __restrict__ cls_p5,
    const unsigned int* __restrict__ flags4, const unsigned int* __restrict__ flags5,
    float* __restrict__ bgpart4, float* __restrict__ bgpart5, int nb4)
{
    const int blk = blockIdx.x;
    const int tid = threadIdx.x;
    float sp = 0.f, cnt = 0.f;
    int scale, oblk;
    if (blk < nb4) {
        scale = 0; oblk = blk;
        int b = blk / 25, j = blk - b * 25;       // 6400/256 = 25 blocks per image
        int cell = j * 256 + tid;                  // always < 6400
        int gidx = b * 6400 + cell;
        unsigned int w = flags4[gidx >> 5];
        if (!((w >> (gidx & 31)) & 1u)) {
            sp = softplusf(cls_p4[(size_t)b * (C_CH * 6400) + cell]);  // channel 0
            cnt = 1.f;
        }
    } else {
        scale = 1; oblk = blk - nb4;
        int b = oblk / 7, j = oblk - b * 7;       // ceil(1600/256) = 7 blocks per image
        int cell = j * 256 + tid;
        if (cell < 1600) {
            int gidx = b * 1600 + cell;
            unsigned int w = flags5[gidx >> 5];
            if (!((w >> (gidx & 31)) & 1u)) {
                sp = softplusf(cls_p5[(size_t)b * (C_CH * 1600) + cell]);
                cnt = 1.f;
            }
        }
    }
    for (int off = 32; off > 0; off >>= 1) {
        sp  += __shfl_down(sp,  off, 64);
        cnt += __shfl_down(cnt, off, 64);
    }
    __shared__ float ss[4][2];
    const int wid = tid >> 6;
    if ((tid & 63) == 0) { ss[wid][0] = sp; ss[wid][1] = cnt; }
    __syncthreads();
    if (tid == 0) {
        float a = ss[0][0] + ss[1][0] + ss[2][0] + ss[3][0];
        float c = ss[0][1] + ss[1][1] + ss[2][1] + ss[3][1];
        float* o = scale ? bgpart5 : bgpart4;
        o[oblk * 2]     = a;
        o[oblk * 2 + 1] = c;
    }
}

__global__ void final_kernel(
    const float* __restrict__ tpart, int nT,
    const float* __restrict__ bgpart4, int nb4,
    const float* __restrict__ bgpart5, int nb5,
    float* __restrict__ out)
{
    float lb = 0.f, lo = 0.f, lc = 0.f, n = 0.f, b4 = 0.f, c4 = 0.f, b5 = 0.f, c5 = 0.f;
    for (int i = threadIdx.x; i < nT; i += 256) {
        lb += tpart[i * 4 + 0]; lo += tpart[i * 4 + 1];
        lc += tpart[i * 4 + 2]; n  += tpart[i * 4 + 3];
    }
    for (int i = threadIdx.x; i < nb4; i += 256) { b4 += bgpart4[2 * i]; c4 += bgpart4[2 * i + 1]; }
    for (int i = threadIdx.x; i < nb5; i += 256) { b5 += bgpart5[2 * i]; c5 += bgpart5[2 * i + 1]; }

    __shared__ float sbuf[4];
    float vals[8] = { lb, lo, lc, n, b4, c4, b5, c5 };
    float tot[8];
    for (int k = 0; k < 8; k++) {
        float v = vals[k];
        for (int off = 32; off > 0; off >>= 1) v += __shfl_down(v, off, 64);
        __syncthreads();
        if ((threadIdx.x & 63) == 0) sbuf[threadIdx.x >> 6] = v;
        __syncthreads();
        tot[k] = sbuf[0] + sbuf[1] + sbuf[2] + sbuf[3];
    }
    if (threadIdx.x == 0) {
        float lbt = tot[0], lot = tot[1], lct = tot[2], nt = tot[3];
        lot += 0.05f * ((tot[5] > 0.f) ? tot[4] / fmaxf(tot[5], 1.f) : 0.f);
        lot += 0.05f * ((tot[7] > 0.f) ? tot[6] / fmaxf(tot[7], 1.f) : 0.f);
        float nd = fmaxf(nt, 1.f);
        if (nt > 0.f) { lbt /= nd; lct /= nd; }
        lot /= fmaxf(nt, 1.f);
        out[0] = 2.0f * lbt + 1.0f * lot + 0.5f * lct;
    }
}

extern "C" void kernel_launch(void* const* d_in, const int* in_sizes, int n_in,
                              void* d_out, int out_size, void* d_ws, size_t ws_size,
                              hipStream_t stream) {
    const float* cls_p4 = (const float*)d_in[0];
    const float* reg_p4 = (const float*)d_in[1];
    const float* cls_p5 = (const float*)d_in[2];
    const float* reg_p5 = (const float*)d_in[3];
    const int*   t4_cls = (const int*)d_in[4];
    const float* t4_box = (const float*)d_in[5];
    const float* t4_mask= (const float*)d_in[6];
    const int*   t5_cls = (const int*)d_in[7];
    const float* t5_box = (const float*)d_in[8];
    const float* t5_mask= (const float*)d_in[9];

    const int B = in_sizes[0] / (C_CH * 6400);   // cls_p4: B x 81 x 80 x 80
    const int T = in_sizes[4] / B;               // t4_cls: B x T
    const int BT = B * T;

    const int fw4 = (B * 6400 + 31) / 32;
    const int fw5 = (B * 1600 + 31) / 32;
    unsigned int* flags4 = (unsigned int*)d_ws;
    unsigned int* flags5 = flags4 + fw4;
    float* tpart = (float*)(flags5 + fw5);
    const int nTblk = (2 * BT + 3) / 4;          // 4 targets per block
    float* bgpart4 = tpart + (size_t)nTblk * 4;
    const int nb4 = B * 25;
    float* bgpart5 = bgpart4 + (size_t)nb4 * 2;
    const int nb5 = B * 7;

    hipMemsetAsync(d_ws, 0, (size_t)(fw4 + fw5) * sizeof(unsigned int), stream);

    target_kernel<<<nTblk, 256, 0, stream>>>(
        cls_p4, reg_p4, cls_p5, reg_p5,
        t4_cls, t4_box, t4_mask, t5_cls, t5_box, t5_mask,
        tpart, flags4, flags5, B, T);

    bg_kernel<<<nb4 + nb5, 256, 0, stream>>>(cls_p4, cls_p5, flags4, flags5,
                                             bgpart4, bgpart5, nb4);

    final_kernel<<<1, 256, 0, stream>>>(tpart, nTblk, bgpart4, nb4, bgpart5, nb5,
                                        (float*)d_out);
}